// Round 4
// baseline (545.767 us; speedup 1.0000x reference)
//
#include <hip/hip_runtime.h>
#include <hip/hip_bf16.h>
#include <hip/hip_cooperative_groups.h>
#include <math.h>

namespace cg = cooperative_groups;

// TreeLSTM, B=8, L=4096, D=300, H=128, 12 levels. Round 4:
//   - convx: x fp32 -> xbf bf16 [32768][320] (zero-padded), vectorized.
//   - leaf_fused: pure-bf16 MFMA GEMM (global_load_lds both operands) with
//     bias+split epilogue fused (gates workspace + leafpost deleted).
//   - levels_all: ONE cooperative kernel for all 12 levels. 256 blocks =
//     32 row-slots x 8 h-groups; each block keeps its 40 KB W-slice resident
//     in LDS across all levels; grid.sync() between levels (replaces 11
//     launches). Lane owns all 5 gates of (row,h) -> in-register epilogue.

typedef __attribute__((ext_vector_type(8))) short bfrag8;   // 8 bf16 = 4 VGPRs
typedef __attribute__((ext_vector_type(4))) float f32x4;

__device__ __forceinline__ float sigf(float x) { return 1.0f / (1.0f + __expf(-x)); }
__device__ __forceinline__ short f2bf(float f) {
    __hip_bfloat16 h = __float2bfloat16(f);
    return *reinterpret_cast<short*>(&h);
}

// ---------------- build weight layouts ----------------
// WcatT bf16 [640][256]  : WcatT[n][k] = (k<128 ? W_l[k][n] : W_r[k-128][n]), n = g*128+h
// WleafT bf16 [256][320] : WleafT[n][k] = k<300 ? W_leaf[k][n] : 0
__global__ __launch_bounds__(256) void reorder_kernel(
    const float* __restrict__ W_l, const float* __restrict__ W_r,
    const float* __restrict__ W_leaf,
    short* __restrict__ WcatT, short* __restrict__ WleafT)
{
    int idx = blockIdx.x * 256 + threadIdx.x;
    if (idx < 163840) {
        int n = idx >> 8, k = idx & 255;
        float v = (k < 128) ? W_l[k * 640 + n] : W_r[(k - 128) * 640 + n];
        WcatT[idx] = f2bf(v);
        return;
    }
    idx -= 163840;
    if (idx < 81920) {
        int n = idx / 320, k = idx - n * 320;
        WleafT[idx] = (k < 300) ? f2bf(W_leaf[k * 256 + n]) : (short)0;
    }
}

// ---------------- x fp32 [32768][300] -> xbf bf16 [32768][320] ----------------
__global__ __launch_bounds__(256) void convx_kernel(
    const float* __restrict__ x, short* __restrict__ xbf)
{
    int u = blockIdx.x * 256 + threadIdx.x;     // 32768*40 units of 8 cols
    int row = u / 40, cc = u - row * 40;
    int c0 = cc * 8;
    const float* src = x + (size_t)row * 300 + c0;
    f32x4 v0 = {0.f,0.f,0.f,0.f}, v1 = {0.f,0.f,0.f,0.f};
    if (c0 + 4 <= 300) v0 = *(const f32x4*)(src);        // rows are 16B-aligned (1200B)
    if (c0 + 8 <= 300) v1 = *(const f32x4*)(src + 4);
    union { bfrag8 v; short s[8]; } o;
    #pragma unroll
    for (int q = 0; q < 4; ++q) { o.s[q] = f2bf(v0[q]); o.s[4 + q] = f2bf(v1[q]); }
    *(bfrag8*)(xbf + (size_t)row * 320 + c0) = o.v;
}

// ---------------- leaf: [32768,320]bf16 @ WleafT[256][320] + bias, split h/c ----------------
// grid (256, 2): y=0 -> cols 0..127 = h (bf16 out), y=1 -> cols 128..255 = c (fp32 out)
__global__ __launch_bounds__(256) void leaf_fused_kernel(
    const short* __restrict__ A,      // xbf
    const short* __restrict__ B,      // WleafT
    const float* __restrict__ bleaf,  // [256]
    short* __restrict__ hD, float* __restrict__ cD)
{
    __shared__ short Als[128 * 64];
    __shared__ short Bls[128 * 64];
    const int tid  = threadIdx.x;
    const int w    = tid >> 6, lane = tid & 63;
    const int quad = lane >> 4, l16 = lane & 15;
    const int mBlk = blockIdx.x * 128, nBlk = blockIdx.y * 128;
    const int waveM = (w >> 1) * 64, waveN = (w & 1) * 64;
    const int lrow = lane >> 3, lslot = lane & 7;

    f32x4 acc[4][4] = {};

    for (int k0 = 0; k0 < 320; k0 += 64) {
        #pragma unroll
        for (int r = 0; r < 4; ++r) {
            int seg = r * 4 + w;
            int row = seg * 8 + lrow;
            int c   = lslot ^ (row & 7);
            const short* gpB = B + (size_t)(nBlk + row) * 320 + k0 + c * 8;
            __builtin_amdgcn_global_load_lds(
                (const __attribute__((address_space(1))) void*)gpB,
                (__attribute__((address_space(3))) void*)(Bls + seg * 512),
                16, 0, 0);
            const short* gpA = A + (size_t)(mBlk + row) * 320 + k0 + c * 8;
            __builtin_amdgcn_global_load_lds(
                (const __attribute__((address_space(1))) void*)gpA,
                (__attribute__((address_space(3))) void*)(Als + seg * 512),
                16, 0, 0);
        }
        __syncthreads();

        #pragma unroll
        for (int ks = 0; ks < 2; ++ks) {
            bfrag8 af[4], bfr[4];
            int cch = ks * 4 + quad;
            #pragma unroll
            for (int i = 0; i < 4; ++i) {
                int row = waveM + i * 16 + l16;
                af[i] = *(const bfrag8*)(Als + row * 64 + (cch ^ (row & 7)) * 8);
            }
            #pragma unroll
            for (int jn = 0; jn < 4; ++jn) {
                int row = waveN + jn * 16 + l16;
                bfr[jn] = *(const bfrag8*)(Bls + row * 64 + (cch ^ (row & 7)) * 8);
            }
            #pragma unroll
            for (int i = 0; i < 4; ++i)
                #pragma unroll
                for (int jn = 0; jn < 4; ++jn)
                    acc[i][jn] = __builtin_amdgcn_mfma_f32_16x16x32_bf16(
                                     af[i], bfr[jn], acc[i][jn], 0, 0, 0);
        }
        __syncthreads();
    }

    // fused epilogue: bias + split (h -> bf16, c -> fp32)
    #pragma unroll
    for (int i = 0; i < 4; ++i) {
        int row0 = mBlk + waveM + i * 16 + quad * 4;
        #pragma unroll
        for (int jn = 0; jn < 4; ++jn) {
            int col = nBlk + waveN + jn * 16 + l16;     // 0..255
            float bv = bleaf[col];
            #pragma unroll
            for (int rg = 0; rg < 4; ++rg) {
                float v = acc[i][jn][rg] + bv;
                int row = row0 + rg;
                if (nBlk == 0) hD[(size_t)row * 128 + col] = f2bf(v);
                else           cD[(size_t)row * 128 + (col - 128)] = v;
            }
        }
    }
}

// ---------------- all 12 levels, cooperative ----------------
// 256 blocks = 32 row-slots (rs) x 8 h-groups (j). Block j owns h in
// [16j,16j+16) for all 5 gates: W-slice rows n' = g*16+hh <-> n = g*128+16j+hh,
// 80 rows x 256 k bf16 = 40 KB, LDS-resident across levels.
// Per level: tiles of 64 rows; wave w = m-tile w (16 rows); per tile:
// stage A (32 KB via global_load_lds), 8 k-iters x (1 A-frag + 5 B-frag + 5 MFMA),
// in-register LSTM epilogue. grid.sync() between levels.
__global__ __launch_bounds__(256) void levels_all_kernel(
    const short* __restrict__ Wcat,   // [640][256] bf16
    const float* __restrict__ bias,   // [640]
    short* h0, float* c0, short* h1, float* c1,
    float* out_final)
{
    cg::grid_group grid = cg::this_grid();
    __shared__ short Wlds[80 * 256];   // 40 KB
    __shared__ short Als[64 * 256];    // 32 KB

    const int tid  = threadIdx.x;
    const int w    = tid >> 6, lane = tid & 63;
    const int quad = lane >> 4, l16 = lane & 15;
    const int j  = blockIdx.x & 7;
    const int rs = blockIdx.x >> 3;
    const int halfrow = lane >> 5;     // 0/1 within a 1KB round (2 rows of 512B)
    const int s31 = lane & 31;

    // ---- load W slice once (40 rounds of 1KB, 10 per wave) ----
    #pragma unroll
    for (int q = 0; q < 10; ++q) {
        int round = w * 10 + q;
        int np = round * 2 + halfrow;          // 0..79
        int c  = s31 ^ (np & 7);               // swizzled global chunk
        int g  = np >> 4, hh = np & 15;
        int ng = g * 128 + j * 16 + hh;
        const char* gp = (const char*)Wcat + (size_t)ng * 512 + c * 16;
        __builtin_amdgcn_global_load_lds(
            (const __attribute__((address_space(1))) void*)gp,
            (__attribute__((address_space(3))) void*)((char*)Wlds + round * 1024),
            16, 0, 0);
    }
    __syncthreads();

    const int h = j * 16 + l16;
    const float bi  = bias[h],       bfl = bias[128 + h], bfr_ = bias[256 + h];
    const float bo  = bias[384 + h], bg  = bias[512 + h];

    const short* hin = h0; const float* cin = c0;
    short* hout = h1; float* cout = c1;
    int M = 16384;

    for (int lev = 1; lev <= 12; ++lev) {
        float* of = (lev == 12) ? out_final : nullptr;
        int T = (M + 63) >> 6;
        for (int t = rs; t < T; t += 32) {
            int tb = t * 64;
            // ---- stage A tile: 64 rows x 256 k (32 rounds, 8 per wave) ----
            #pragma unroll
            for (int q = 0; q < 8; ++q) {
                int round = w * 8 + q;
                int rl = round * 2 + halfrow;      // 0..63
                int c  = s31 ^ (rl & 7);
                int gr = tb + rl; if (gr >= M) gr = 0;
                const char* gp = (const char*)hin + (size_t)gr * 512 + c * 16;
                __builtin_amdgcn_global_load_lds(
                    (const __attribute__((address_space(1))) void*)gp,
                    (__attribute__((address_space(3))) void*)((char*)Als + round * 1024),
                    16, 0, 0);
            }
            __syncthreads();

            f32x4 acc[5] = {};
            const int rowl = w * 16 + l16;
            const char* abase = (const char*)Als + rowl * 512;
            #pragma unroll
            for (int kk = 0; kk < 8; ++kk) {
                int ca = kk * 4 + quad;
                bfrag8 af = *(const bfrag8*)(abase + ((ca ^ (rowl & 7)) << 4));
                #pragma unroll
                for (int g = 0; g < 5; ++g) {
                    int np = g * 16 + l16;
                    bfrag8 bf = *(const bfrag8*)((const char*)Wlds + np * 512
                                                 + ((ca ^ (np & 7)) << 4));
                    acc[g] = __builtin_amdgcn_mfma_f32_16x16x32_bf16(af, bf, acc[g], 0, 0, 0);
                }
            }
            __syncthreads();

            // ---- in-register LSTM epilogue ----
            #pragma unroll
            for (int rg = 0; rg < 4; ++rg) {
                int row = tb + w * 16 + quad * 4 + rg;
                if (row < M) {
                    float gi  = acc[0][rg] + bi;
                    float gfl = acc[1][rg] + bfl;
                    float gfr = acc[2][rg] + bfr_;
                    float go  = acc[3][rg] + bo;
                    float gg  = acc[4][rg] + bg;
                    float cl  = cin[(size_t)(2 * row) * 128 + h];
                    float cr  = cin[(size_t)(2 * row + 1) * 128 + h];
                    float cn  = sigf(gfl) * cl + sigf(gfr) * cr + sigf(gi) * tanhf(gg);
                    float hn  = sigf(go) * tanhf(cn);
                    if (of) {
                        of[(size_t)row * 128 + h] = hn;
                    } else {
                        hout[(size_t)row * 128 + h] = f2bf(hn);
                        cout[(size_t)row * 128 + h] = cn;
                    }
                }
            }
        }
        grid.sync();
        const short* nh = hin; const float* nc = cin;
        hin = hout; cin = cout;
        hout = (short*)nh; cout = (float*)nc;
        M >>= 1;
    }
}

extern "C" void kernel_launch(void* const* d_in, const int* in_sizes, int n_in,
                              void* d_out, int out_size, void* d_ws, size_t ws_size,
                              hipStream_t stream)
{
    const float* x      = (const float*)d_in[0];
    const float* W_leaf = (const float*)d_in[1];
    const float* b_leaf = (const float*)d_in[2];
    const float* W_l    = (const float*)d_in[3];
    const float* W_r    = (const float*)d_in[4];
    const float* b      = (const float*)d_in[5];
    float* out = (float*)d_out;

    // workspace (~59 MB)
    char* p = (char*)d_ws;
    short* xbf    = (short*)p; p += (size_t)32768 * 320 * 2;   // 21.0 MB
    short* h0     = (short*)p; p += (size_t)32768 * 128 * 2;   //  8.4 MB
    short* h1     = (short*)p; p += (size_t)16384 * 128 * 2;   //  4.2 MB
    float* c0     = (float*)p; p += (size_t)32768 * 128 * 4;   // 16.8 MB
    float* c1     = (float*)p; p += (size_t)16384 * 128 * 4;   //  8.4 MB
    short* WcatT  = (short*)p; p += (size_t)640 * 256 * 2;
    short* WleafT = (short*)p; p += (size_t)256 * 320 * 2;

    reorder_kernel<<<(163840 + 81920) / 256, 256, 0, stream>>>(
        W_l, W_r, W_leaf, WcatT, WleafT);
    convx_kernel<<<(32768 * 40) / 256, 256, 0, stream>>>(x, xbf);
    leaf_fused_kernel<<<dim3(256, 2), 256, 0, stream>>>(
        xbf, WleafT, b_leaf, h0, c0);

    void* cargs[] = { (void*)&WcatT, (void*)&b, (void*)&h0, (void*)&c0,
                      (void*)&h1, (void*)&c1, (void*)&out };
    hipLaunchCooperativeKernel((void*)levels_all_kernel, dim3(256), dim3(256),
                               cargs, 0, stream);
}

// Round 5
// 388.041 us; speedup vs baseline: 1.4065x; 1.4065x over previous
//
#include <hip/hip_runtime.h>
#include <hip/hip_bf16.h>
#include <math.h>

// TreeLSTM, B=8, L=4096, D=300, H=128, 12 levels. Round 5:
// All GEMM operands stored CHUNK-MAJOR in global: unit u = [c = k/8][row] of
// 16B (8 bf16). -> global_load_lds rounds are contiguous 1KB/instr, LDS frag
// reads are conflict-free (bank quad = row%8, spread by l16). Per-level
// launches, fused LSTM epilogue, double-buffered K-loop.

typedef __attribute__((ext_vector_type(8))) short bfrag8;   // 8 bf16 = 4 VGPRs
typedef __attribute__((ext_vector_type(4))) float f32x4;
typedef __attribute__((ext_vector_type(4))) short s16x4;

__device__ __forceinline__ float sigf(float x) { return 1.0f / (1.0f + __expf(-x)); }
__device__ __forceinline__ short f2bf(float f) {
    __hip_bfloat16 h = __float2bfloat16(f);
    return *reinterpret_cast<short*>(&h);
}
#define GLDS(gp, lp) __builtin_amdgcn_global_load_lds( \
    (const __attribute__((address_space(1))) void*)(gp), \
    (__attribute__((address_space(3))) void*)(lp), 16, 0, 0)

// ---------------- weight reorder (once, tiny) ----------------
// Wcat_ch : chunk layout [c:0..31][n:0..640) of k-column n; n = g*128+h,
//           k<128 -> W_l[k][n], else W_r[k-128][n].
// Wleaf_ch: chunk layout [c:0..39][n:0..256), k<300 valid else 0.
__global__ __launch_bounds__(256) void reorder_kernel(
    const float* __restrict__ W_l, const float* __restrict__ W_r,
    const float* __restrict__ W_leaf,
    short* __restrict__ Wcat_ch, short* __restrict__ Wleaf_ch)
{
    int idx = blockIdx.x * 256 + threadIdx.x;
    if (idx < 163840) {
        int n = idx >> 8, k = idx & 255;
        float v = (k < 128) ? W_l[k * 640 + n] : W_r[(k - 128) * 640 + n];
        Wcat_ch[(((size_t)(k >> 3)) * 640 + n) * 8 + (k & 7)] = f2bf(v);
        return;
    }
    idx -= 163840;
    if (idx < 81920) {
        int n = idx / 320, k = idx - n * 320;
        short v = (k < 300) ? f2bf(W_leaf[k * 256 + n]) : (short)0;
        Wleaf_ch[(((size_t)(k >> 3)) * 256 + n) * 8 + (k & 7)] = v;
    }
}

// ---------------- x fp32 [32768][300] -> xbf chunk-major [40][32768] units ----------------
// LDS transpose: coalesced row reads AND coalesced chunk writes.
__global__ __launch_bounds__(256) void convx_kernel(
    const float* __restrict__ x, short* __restrict__ xbf)
{
    __shared__ short Ls[64 * 328];          // padded stride 328 (41 units) -> spread banks
    const int tid = threadIdx.x;
    const int R0 = blockIdx.x * 64;
    for (int i = tid; i < 64 * 75; i += 256) {          // 300 floats = 75 f32x4 per row
        int r = i / 75, q = i - r * 75;
        f32x4 v = *(const f32x4*)(x + (size_t)(R0 + r) * 300 + q * 4);
        s16x4 o;
        #pragma unroll
        for (int t = 0; t < 4; ++t) o[t] = f2bf(v[t]);
        *(s16x4*)(Ls + r * 328 + q * 4) = o;
    }
    for (int i = tid; i < 64 * 20; i += 256) {          // zero-pad cols 300..319
        int r = i / 20, q = i - r * 20;
        Ls[r * 328 + 300 + q] = 0;
    }
    __syncthreads();
    for (int i = tid; i < 40 * 64; i += 256) {          // write chunks, 1KB per 64-lane group
        int c = i >> 6, r = i & 63;
        bfrag8 v = *(const bfrag8*)(Ls + r * 328 + c * 8);
        *(bfrag8*)(xbf + ((size_t)c * 32768 + R0 + r) * 8) = v;
    }
}

// ---------------- leaf: [32768,320]@[320,256] + bias, split h/c ----------------
// A = xbf chunks [40][32768]; B = Wleaf_ch [40][256]. grid (256,2): y=0 h-half, y=1 c-half.
__global__ __launch_bounds__(256) void leaf_kernel(
    const short* __restrict__ A, const short* __restrict__ B,
    const float* __restrict__ bleaf,
    short* __restrict__ hD,       // level-1 A, chunk layout [32][16384] units
    float* __restrict__ cD)       // [32768][128] fp32
{
    __shared__ short Als[8 * 128 * 8];   // [c_local][row] 16KB
    __shared__ short Bls[8 * 128 * 8];
    const int tid  = threadIdx.x;
    const int w    = tid >> 6, lane = tid & 63;
    const int quad = lane >> 4, l16 = lane & 15;
    const int mBlk = blockIdx.x * 128, nBlk = blockIdx.y * 128;
    const int waveM = (w >> 1) * 64, waveN = (w & 1) * 64;

    f32x4 acc[4][4] = {};

    for (int k0 = 0; k0 < 40; k0 += 8) {
        #pragma unroll
        for (int q = 0; q < 4; ++q) {
            int rr = w * 4 + q, cl = rr >> 1, rh = rr & 1;
            GLDS(A + ((size_t)(k0 + cl) * 32768 + mBlk + rh * 64 + lane) * 8,
                 (char*)Als + rr * 1024);
            GLDS(B + ((size_t)(k0 + cl) * 256 + nBlk + rh * 64 + lane) * 8,
                 (char*)Bls + rr * 1024);
        }
        __syncthreads();
        #pragma unroll
        for (int ks = 0; ks < 2; ++ks) {
            int ca = ks * 4 + quad;
            bfrag8 af[4], bf[4];
            #pragma unroll
            for (int i = 0; i < 4; ++i)
                af[i] = *(const bfrag8*)(Als + (ca * 128 + waveM + i * 16 + l16) * 8);
            #pragma unroll
            for (int j = 0; j < 4; ++j)
                bf[j] = *(const bfrag8*)(Bls + (ca * 128 + waveN + j * 16 + l16) * 8);
            #pragma unroll
            for (int i = 0; i < 4; ++i)
                #pragma unroll
                for (int j = 0; j < 4; ++j)
                    acc[i][j] = __builtin_amdgcn_mfma_f32_16x16x32_bf16(
                                    af[i], bf[j], acc[i][j], 0, 0, 0);
        }
        __syncthreads();
    }

    #pragma unroll
    for (int i = 0; i < 4; ++i) {
        int row0 = mBlk + waveM + i * 16 + quad * 4;
        #pragma unroll
        for (int j = 0; j < 4; ++j) {
            int col = nBlk + waveN + j * 16 + l16;
            float bv = bleaf[col];
            #pragma unroll
            for (int rg = 0; rg < 4; ++rg) {
                float v = acc[i][j][rg] + bv;
                int m = row0 + rg;
                if (nBlk == 0) {
                    int hc = col;    // h output -> level-1 A chunk layout, Mn=16384
                    hD[(((size_t)((m & 1) * 16 + (hc >> 3))) * 16384 + (m >> 1)) * 8
                       + (hc & 7)] = f2bf(v);
                } else {
                    cD[(size_t)m * 128 + (col - 128)] = v;
                }
            }
        }
    }
}

// ---------------- one tree level: fused GEMM + LSTM, double-buffered ----------------
// A chunk layout [32][M] units; Wch [32][640]; out h -> chunk layout [32][M/2].
__global__ __launch_bounds__(256) void level_kernel(
    const short* __restrict__ A, const float* __restrict__ cprev,
    const short* __restrict__ Wch, const float* __restrict__ bias,
    short* __restrict__ hout, float* __restrict__ cout,
    int M, float* __restrict__ out_final)
{
    __shared__ short Als[2][4 * 64 * 8];     // 2 x 4KB  [c_local][row]
    __shared__ short Bls[2][4 * 640 * 8];    // 2 x 40KB [c_local][n]
    const int tid  = threadIdx.x;
    const int w    = tid >> 6, lane = tid & 63;
    const int quad = lane >> 4, l16 = lane & 15;
    const int tb   = blockIdx.x * 64;

    f32x4 acc[4][10] = {};    // [m-tile][g*2+hf]

    auto stage = [&](int s, int buf) {
        GLDS(A + ((size_t)(s * 4 + w) * M + tb + lane) * 8,
             (char*)Als[buf] + w * 1024);
        #pragma unroll
        for (int q = 0; q < 10; ++q)
            GLDS(Wch + ((size_t)(s * 4 + w) * 640 + q * 64 + lane) * 8,
                 (char*)Bls[buf] + (w * 10 + q) * 1024);
    };

    stage(0, 0);
    #pragma unroll
    for (int s = 0; s < 8; ++s) {
        __syncthreads();                       // drains stage(s) -> buf[s&1] ready
        if (s < 7) stage(s + 1, (s + 1) & 1);  // overlaps with compute below
        const short* Ab = Als[s & 1];
        const short* Bb = Bls[s & 1];
        bfrag8 af[4];
        #pragma unroll
        for (int mt = 0; mt < 4; ++mt)
            af[mt] = *(const bfrag8*)(Ab + (quad * 64 + mt * 16 + l16) * 8);
        #pragma unroll
        for (int g = 0; g < 5; ++g) {
            #pragma unroll
            for (int hf = 0; hf < 2; ++hf) {
                int n = g * 128 + w * 32 + hf * 16 + l16;
                bfrag8 bf = *(const bfrag8*)(Bb + (quad * 640 + n) * 8);
                #pragma unroll
                for (int mt = 0; mt < 4; ++mt)
                    acc[mt][g * 2 + hf] = __builtin_amdgcn_mfma_f32_16x16x32_bf16(
                                              af[mt], bf, acc[mt][g * 2 + hf], 0, 0, 0);
            }
        }
    }

    const int Mn = M >> 1;
    #pragma unroll
    for (int mt = 0; mt < 4; ++mt) {
        #pragma unroll
        for (int rg = 0; rg < 4; ++rg) {
            int m = tb + mt * 16 + quad * 4 + rg;
            if (m < M) {
                #pragma unroll
                for (int hf = 0; hf < 2; ++hf) {
                    int h = w * 32 + hf * 16 + l16;
                    float gi  = acc[mt][0 + hf][rg] + bias[h];
                    float gfl = acc[mt][2 + hf][rg] + bias[128 + h];
                    float gfr = acc[mt][4 + hf][rg] + bias[256 + h];
                    float go  = acc[mt][6 + hf][rg] + bias[384 + h];
                    float gg  = acc[mt][8 + hf][rg] + bias[512 + h];
                    float cl  = cprev[(size_t)(2 * m) * 128 + h];
                    float cr  = cprev[(size_t)(2 * m + 1) * 128 + h];
                    float cn  = sigf(gfl) * cl + sigf(gfr) * cr + sigf(gi) * tanhf(gg);
                    float hn  = sigf(go) * tanhf(cn);
                    if (out_final) {
                        out_final[(size_t)m * 128 + h] = hn;
                    } else {
                        hout[(((size_t)((m & 1) * 16 + (h >> 3))) * Mn + (m >> 1)) * 8
                             + (h & 7)] = f2bf(hn);
                        cout[(size_t)m * 128 + h] = cn;
                    }
                }
            }
        }
    }
}

extern "C" void kernel_launch(void* const* d_in, const int* in_sizes, int n_in,
                              void* d_out, int out_size, void* d_ws, size_t ws_size,
                              hipStream_t stream)
{
    const float* x      = (const float*)d_in[0];
    const float* W_leaf = (const float*)d_in[1];
    const float* b_leaf = (const float*)d_in[2];
    const float* W_l    = (const float*)d_in[3];
    const float* W_r    = (const float*)d_in[4];
    const float* b      = (const float*)d_in[5];
    float* out = (float*)d_out;

    // workspace (~59 MB)
    char* p = (char*)d_ws;
    short* xbf   = (short*)p; p += (size_t)40 * 32768 * 16;        // 21.0 MB
    short* hA    = (short*)p; p += (size_t)32 * 16384 * 16 + 1024; //  8.4 MB (+pad)
    short* hB    = (short*)p; p += (size_t)32 * 8192 * 16 + 1024;  //  4.2 MB (+pad)
    float* c0    = (float*)p; p += (size_t)32768 * 128 * 4;        // 16.8 MB
    float* c1    = (float*)p; p += (size_t)16384 * 128 * 4;        //  8.4 MB
    short* WcatC = (short*)p; p += (size_t)32 * 640 * 16;          // 320 KB
    short* WlfC  = (short*)p; p += (size_t)40 * 256 * 16;          // 160 KB

    reorder_kernel<<<960, 256, 0, stream>>>(W_l, W_r, W_leaf, WcatC, WlfC);
    convx_kernel<<<512, 256, 0, stream>>>(x, xbf);
    leaf_kernel<<<dim3(256, 2), 256, 0, stream>>>(xbf, WlfC, b_leaf, hA, c0);

    const short* hin = hA; const float* cin = c0;
    int M = 16384;
    for (int lev = 1; lev <= 12; ++lev) {
        short* ho = (lev & 1) ? hB : hA;
        float* co = (lev & 1) ? c1 : c0;
        float* of = (lev == 12) ? out : nullptr;
        level_kernel<<<dim3((M + 63) / 64), 256, 0, stream>>>(
            hin, cin, WcatC, b, ho, co, M, of);
        hin = ho; cin = co;
        M >>= 1;
    }
}

// Round 6
// 207.371 us; speedup vs baseline: 2.6318x; 1.8712x over previous
//
#include <hip/hip_runtime.h>
#include <hip/hip_bf16.h>
#include <math.h>

// TreeLSTM, B=8, L=4096, D=300, H=128, 12 levels. Round 6:
// WEIGHT-STATIONARY level kernel: grid (T row-tiles, 8 h-groups). Block (t,j)
// owns 64 rows x 16 h x 5 gates; its 40 KB W-slice lives in 160 VGPRs/lane
// (loaded once, parallel prologue) -> K-loop = 1 ds_read_b128 + 5 MFMA per
// k-step, no W streaming (this was the 27us/level killer in R5: every block
// pulled the full 320 KB W through LDS; fatal at deep levels with few CUs).
// Chunk-major global layouts (R5) kept: unit u = [c=k/8][row] of 16B.

typedef __attribute__((ext_vector_type(8))) short bfrag8;   // 8 bf16 = 4 VGPRs
typedef __attribute__((ext_vector_type(4))) float f32x4;
typedef __attribute__((ext_vector_type(4))) short s16x4;

__device__ __forceinline__ float sigf(float x) { return 1.0f / (1.0f + __expf(-x)); }
__device__ __forceinline__ short f2bf(float f) {
    __hip_bfloat16 h = __float2bfloat16(f);
    return *reinterpret_cast<short*>(&h);
}
#define GLDS(gp, lp) __builtin_amdgcn_global_load_lds( \
    (const __attribute__((address_space(1))) void*)(gp), \
    (__attribute__((address_space(3))) void*)(lp), 16, 0, 0)

// ---------------- weight reorder (once, tiny) ----------------
// Wcat_ch : chunk layout [c:0..31][n:0..640) ; n = g*128+h ; k<128 -> W_l, else W_r.
// Wleaf_ch: chunk layout [c:0..39][n:0..256) ; k<300 valid else 0.
__global__ __launch_bounds__(256) void reorder_kernel(
    const float* __restrict__ W_l, const float* __restrict__ W_r,
    const float* __restrict__ W_leaf,
    short* __restrict__ Wcat_ch, short* __restrict__ Wleaf_ch)
{
    int idx = blockIdx.x * 256 + threadIdx.x;
    if (idx < 163840) {
        int n = idx >> 8, k = idx & 255;
        float v = (k < 128) ? W_l[k * 640 + n] : W_r[(k - 128) * 640 + n];
        Wcat_ch[(((size_t)(k >> 3)) * 640 + n) * 8 + (k & 7)] = f2bf(v);
        return;
    }
    idx -= 163840;
    if (idx < 81920) {
        int n = idx / 320, k = idx - n * 320;
        short v = (k < 300) ? f2bf(W_leaf[k * 256 + n]) : (short)0;
        Wleaf_ch[(((size_t)(k >> 3)) * 256 + n) * 8 + (k & 7)] = v;
    }
}

// ---------------- x fp32 [32768][300] -> xbf chunk-major [40][32768] units ----------------
__global__ __launch_bounds__(256) void convx_kernel(
    const float* __restrict__ x, short* __restrict__ xbf)
{
    __shared__ short Ls[64 * 328];
    const int tid = threadIdx.x;
    const int R0 = blockIdx.x * 64;
    for (int i = tid; i < 64 * 75; i += 256) {
        int r = i / 75, q = i - r * 75;
        f32x4 v = *(const f32x4*)(x + (size_t)(R0 + r) * 300 + q * 4);
        s16x4 o;
        #pragma unroll
        for (int t = 0; t < 4; ++t) o[t] = f2bf(v[t]);
        *(s16x4*)(Ls + r * 328 + q * 4) = o;
    }
    for (int i = tid; i < 64 * 20; i += 256) {
        int r = i / 20, q = i - r * 20;
        Ls[r * 328 + 300 + q] = 0;
    }
    __syncthreads();
    for (int i = tid; i < 40 * 64; i += 256) {
        int c = i >> 6, r = i & 63;
        bfrag8 v = *(const bfrag8*)(Ls + r * 328 + c * 8);
        *(bfrag8*)(xbf + ((size_t)c * 32768 + R0 + r) * 8) = v;
    }
}

// ---------------- leaf: [32768,320]@[320,256] + bias, split h/c ----------------
__global__ __launch_bounds__(256) void leaf_kernel(
    const short* __restrict__ A, const short* __restrict__ B,
    const float* __restrict__ bleaf,
    short* __restrict__ hD,       // level-1 A, chunk layout [32][16384] units
    float* __restrict__ cD)       // [32768][128] fp32
{
    __shared__ short Als[8 * 128 * 8];
    __shared__ short Bls[8 * 128 * 8];
    const int tid  = threadIdx.x;
    const int w    = tid >> 6, lane = tid & 63;
    const int quad = lane >> 4, l16 = lane & 15;
    const int mBlk = blockIdx.x * 128, nBlk = blockIdx.y * 128;
    const int waveM = (w >> 1) * 64, waveN = (w & 1) * 64;

    f32x4 acc[4][4] = {};

    for (int k0 = 0; k0 < 40; k0 += 8) {
        #pragma unroll
        for (int q = 0; q < 4; ++q) {
            int rr = w * 4 + q, cl = rr >> 1, rh = rr & 1;
            GLDS(A + ((size_t)(k0 + cl) * 32768 + mBlk + rh * 64 + lane) * 8,
                 (char*)Als + rr * 1024);
            GLDS(B + ((size_t)(k0 + cl) * 256 + nBlk + rh * 64 + lane) * 8,
                 (char*)Bls + rr * 1024);
        }
        __syncthreads();
        #pragma unroll
        for (int ks = 0; ks < 2; ++ks) {
            int ca = ks * 4 + quad;
            bfrag8 af[4], bf[4];
            #pragma unroll
            for (int i = 0; i < 4; ++i)
                af[i] = *(const bfrag8*)(Als + (ca * 128 + waveM + i * 16 + l16) * 8);
            #pragma unroll
            for (int jn = 0; jn < 4; ++jn)
                bf[jn] = *(const bfrag8*)(Bls + (ca * 128 + waveN + jn * 16 + l16) * 8);
            #pragma unroll
            for (int i = 0; i < 4; ++i)
                #pragma unroll
                for (int jn = 0; jn < 4; ++jn)
                    acc[i][jn] = __builtin_amdgcn_mfma_f32_16x16x32_bf16(
                                     af[i], bf[jn], acc[i][jn], 0, 0, 0);
        }
        __syncthreads();
    }

    #pragma unroll
    for (int i = 0; i < 4; ++i) {
        int row0 = mBlk + waveM + i * 16 + quad * 4;
        #pragma unroll
        for (int jn = 0; jn < 4; ++jn) {
            int col = nBlk + waveN + jn * 16 + l16;
            float bv = bleaf[col];
            #pragma unroll
            for (int rg = 0; rg < 4; ++rg) {
                float v = acc[i][jn][rg] + bv;
                int m = row0 + rg;
                if (nBlk == 0) {
                    int hc = col;
                    hD[(((size_t)((m & 1) * 16 + (hc >> 3))) * 16384 + (m >> 1)) * 8
                       + (hc & 7)] = f2bf(v);
                } else {
                    cD[(size_t)m * 128 + (col - 128)] = v;
                }
            }
        }
    }
}

// ---------------- weight-stationary level kernel ----------------
// grid (T, 8): x = row-tile (64 rows), y = h-group j (16 h x 5 gates = 80 n).
// W-slice in 160 VGPRs/lane; A tile 32 KB staged once (8 GLDS/wave in flight);
// fused LSTM epilogue; h written in next level's chunk layout.
__global__ __launch_bounds__(256, 2) void level_ws_kernel(
    const short* __restrict__ A,      // [32][M] chunk units
    const float* __restrict__ cprev,  // [2M][128] fp32
    const short* __restrict__ Wch,    // [32][640] chunk units
    const float* __restrict__ bias,   // [640]
    short* __restrict__ hout, float* __restrict__ cout,
    int M, float* __restrict__ out_final)
{
    __shared__ short Als[32 * 64 * 8];   // 32 KB, [c][row]
    const int tid  = threadIdx.x;
    const int w    = tid >> 6, lane = tid & 63;
    const int quad = lane >> 4, l16 = lane & 15;
    const int j  = blockIdx.y;
    const int tb = blockIdx.x * 64;
    const int h  = j * 16 + l16;

    // ---- stage A tile: 8 GLDS per wave, all outstanding at once ----
    {
        int row = tb + lane; if (row >= M) row = 0;
        #pragma unroll
        for (int s = 0; s < 8; ++s)
            GLDS(A + ((size_t)(s * 4 + w) * M + row) * 8,
                 (char*)Als + (s * 4 + w) * 1024);
    }

    // ---- W fragments: loaded once, stay in VGPRs (overlaps A staging) ----
    bfrag8 Wfr[5][8];
    #pragma unroll
    for (int g = 0; g < 5; ++g)
        #pragma unroll
        for (int s = 0; s < 8; ++s)
            Wfr[g][s] = *(const bfrag8*)(Wch + ((size_t)(s * 4 + quad) * 640
                                                + g * 128 + h) * 8);
    const float bi  = bias[h],       bfl = bias[128 + h], bfr_ = bias[256 + h];
    const float bo  = bias[384 + h], bg  = bias[512 + h];

    __syncthreads();

    // ---- K-loop: 8 ksteps x (1 ds_read_b128 + 5 MFMA) ----
    f32x4 acc[5] = {};
    #pragma unroll
    for (int s = 0; s < 8; ++s) {
        bfrag8 af = *(const bfrag8*)(Als + ((s * 4 + quad) * 64 + w * 16 + l16) * 8);
        #pragma unroll
        for (int g = 0; g < 5; ++g)
            acc[g] = __builtin_amdgcn_mfma_f32_16x16x32_bf16(af, Wfr[g][s], acc[g], 0, 0, 0);
    }

    // ---- fused LSTM epilogue: lane holds all 5 gates of (row, h) ----
    const int Mn = M >> 1;
    #pragma unroll
    for (int rg = 0; rg < 4; ++rg) {
        int m = tb + w * 16 + quad * 4 + rg;
        if (m < M) {
            float gi  = acc[0][rg] + bi;
            float gfl = acc[1][rg] + bfl;
            float gfr = acc[2][rg] + bfr_;
            float go  = acc[3][rg] + bo;
            float gg  = acc[4][rg] + bg;
            float cl  = cprev[(size_t)(2 * m) * 128 + h];
            float cr  = cprev[(size_t)(2 * m + 1) * 128 + h];
            float cn  = sigf(gfl) * cl + sigf(gfr) * cr + sigf(gi) * tanhf(gg);
            float hn  = sigf(go) * tanhf(cn);
            if (out_final) {
                out_final[(size_t)m * 128 + h] = hn;
            } else {
                hout[(((size_t)((m & 1) * 16 + (h >> 3))) * Mn + (m >> 1)) * 8
                     + (h & 7)] = f2bf(hn);
                cout[(size_t)m * 128 + h] = cn;
            }
        }
    }
}

extern "C" void kernel_launch(void* const* d_in, const int* in_sizes, int n_in,
                              void* d_out, int out_size, void* d_ws, size_t ws_size,
                              hipStream_t stream)
{
    const float* x      = (const float*)d_in[0];
    const float* W_leaf = (const float*)d_in[1];
    const float* b_leaf = (const float*)d_in[2];
    const float* W_l    = (const float*)d_in[3];
    const float* W_r    = (const float*)d_in[4];
    const float* b      = (const float*)d_in[5];
    float* out = (float*)d_out;

    // workspace (~59 MB)
    char* p = (char*)d_ws;
    short* xbf   = (short*)p; p += (size_t)40 * 32768 * 16;        // 21.0 MB
    short* hA    = (short*)p; p += (size_t)32 * 16384 * 16 + 1024; //  8.4 MB
    short* hB    = (short*)p; p += (size_t)32 * 8192 * 16 + 1024;  //  4.2 MB
    float* c0    = (float*)p; p += (size_t)32768 * 128 * 4;        // 16.8 MB
    float* c1    = (float*)p; p += (size_t)16384 * 128 * 4;        //  8.4 MB
    short* WcatC = (short*)p; p += (size_t)32 * 640 * 16;          // 320 KB
    short* WlfC  = (short*)p; p += (size_t)40 * 256 * 16;          // 160 KB

    reorder_kernel<<<960, 256, 0, stream>>>(W_l, W_r, W_leaf, WcatC, WlfC);
    convx_kernel<<<512, 256, 0, stream>>>(x, xbf);
    leaf_kernel<<<dim3(256, 2), 256, 0, stream>>>(xbf, WlfC, b_leaf, hA, c0);

    const short* hin = hA; const float* cin = c0;
    int M = 16384;
    for (int lev = 1; lev <= 12; ++lev) {
        short* ho = (lev & 1) ? hB : hA;
        float* co = (lev & 1) ? c1 : c0;
        float* of = (lev == 12) ? out : nullptr;
        level_ws_kernel<<<dim3((M + 63) / 64, 8), 256, 0, stream>>>(
            hin, cin, WcatC, b, ho, co, M, of);
        hin = ho; cin = co;
        M >>= 1;
    }
}